// Round 1
// baseline (1044.204 us; speedup 1.0000x reference)
//
#include <hip/hip_runtime.h>
#include <stdint.h>
#include <stddef.h>

// WanSelfAttention on gfx950.
// R5: XOR chunk-swizzle on all LDS tiles (Ks/Vs/Ps in k_attn, As/Bs in k_gemm)
// to kill 16-way / 8-way bank conflicts. global_load_lds forces contiguous LDS
// layout, so the swizzle is applied by permuting each lane's GLOBAL source
// address at staging time; fragment reads use the same XOR.
// R6: T5 s_setprio(1) around the pure-MFMA clusters in k_attn (m191: +4-7% on
// independent-block attention; NOT applied to k_gemm where it measured ~0).

typedef __attribute__((ext_vector_type(8))) short short8;
typedef __attribute__((ext_vector_type(4))) float f32x4;
typedef __attribute__((ext_vector_type(4))) unsigned short ushort4v;
typedef __attribute__((address_space(1))) uint32_t gu32;
typedef __attribute__((address_space(3))) uint32_t lu32;

__device__ __forceinline__ float btof(unsigned short u){
  union { float f; uint32_t i; } x; x.i = ((uint32_t)u) << 16; return x.f;
}
__device__ __forceinline__ unsigned short ftob(float f){
  uint32_t u = __builtin_bit_cast(uint32_t, f);
  u += 0x7fffu + ((u >> 16) & 1u);   // RTNE (finite inputs only)
  return (unsigned short)(u >> 16);
}
__device__ __forceinline__ float rb(float f){ return btof(ftob(f)); }

__device__ __forceinline__ void async_cp16(const void* g, void* l){
  __builtin_amdgcn_global_load_lds((gu32*)g, (lu32*)l, 16, 0, 0);
}

// ---------------- converters ----------------

__global__ __launch_bounds__(256) void k_convert_x(const float* __restrict__ x,
                                                   unsigned short* __restrict__ xb){
  int i = (blockIdx.x * 256 + threadIdx.x) * 4;
  float4 v = *(const float4*)(x + i);
  ushort4v o = { ftob(v.x), ftob(v.y), ftob(v.z), ftob(v.w) };
  *(ushort4v*)(xb + i) = o;
}

__global__ __launch_bounds__(256) void k_bias(const float* __restrict__ bq,
                                              const float* __restrict__ bk,
                                              const float* __restrict__ bv,
                                              float* __restrict__ bias9){
  int i = blockIdx.x * 256 + threadIdx.x;     // 0..9215
  const float* s = (i < 3072) ? bq : ((i < 6144) ? bk : bv);
  bias9[i] = s[i % 3072];
}

// Transpose f32 weights (K x N, row-major) into bf16 W^T (N x K) rows.
__global__ __launch_bounds__(256) void k_wt(const float* __restrict__ wq,
                                            const float* __restrict__ wk,
                                            const float* __restrict__ wv,
                                            const float* __restrict__ wo,
                                            unsigned short* __restrict__ WTqkv,
                                            unsigned short* __restrict__ woT){
  __shared__ float tile[64][65];
  int k0 = blockIdx.x * 64;
  int n0g = blockIdx.y * 64;
  const float* src; unsigned short* dst; int col0, drow0;
  if (n0g < 9216){
    int sel = n0g / 3072;
    src = (sel == 0) ? wq : ((sel == 1) ? wk : wv);
    col0 = n0g % 3072; dst = WTqkv; drow0 = n0g;
  } else { src = wo; col0 = n0g - 9216; dst = woT; drow0 = n0g - 9216; }
  for (int i = 0; i < 16; i++){
    int idx = i * 256 + threadIdx.x;
    int r = idx >> 6, c = idx & 63;
    tile[r][c] = src[(size_t)(k0 + r) * 3072 + col0 + c];
  }
  __syncthreads();
  for (int i = 0; i < 16; i++){
    int idx = i * 256 + threadIdx.x;
    int rr = idx >> 6, cc = idx & 63;
    dst[(size_t)(drow0 + rr) * 3072 + k0 + cc] = ftob(tile[cc][rr]);
  }
}

// ---------------- GEMM: C[m][n] = sum_k A[m][k]*BT[n][k] + bias[n] ----------------
// 128x128 tile, BK=32, 4 waves (2x2), 4x4 MFMA tiles per wave.
// LDS rows = 32 elems = 64 B = 4 chunks of 16 B; swizzle chunk' = chunk ^ (row&3).
template <bool OUT_BF16>
__global__ __launch_bounds__(256) void k_gemm(const unsigned short* __restrict__ A,
                                              const unsigned short* __restrict__ BT,
                                              const float* __restrict__ bias,
                                              void* __restrict__ Cout, int N, int K){
  __shared__ __align__(16) unsigned short As[128 * 32];
  __shared__ __align__(16) unsigned short Bs[128 * 32];
  int tid = threadIdx.x;
  int w = tid >> 6, lane = tid & 63;
  int quad = lane >> 4, l16 = lane & 15;
  int m0 = blockIdx.y * 128, n0 = blockIdx.x * 128;
  int wr = w >> 1, wc = w & 1;

  f32x4 acc[4][4] = {};

  int srow = lane >> 2;                              // LDS row this lane fills
  int scol = ((lane & 3) ^ (srow & 3)) * 8;          // swizzled global chunk
  const unsigned short* Abase = A + (size_t)(m0 + w * 32 + srow) * K + scol;
  const unsigned short* Bbase = BT + (size_t)(n0 + w * 32 + srow) * K + scol;
  unsigned short* AsW = As + (w * 32) * 32;  // uniform per wave; HW adds lane*16B
  unsigned short* BsW = Bs + (w * 32) * 32;

  for (int kt = 0; kt < K; kt += 32){
    __syncthreads();
    async_cp16(Abase + kt, AsW);
    async_cp16(Abase + kt + (size_t)16 * K, AsW + 16 * 32);
    async_cp16(Bbase + kt, BsW);
    async_cp16(Bbase + kt + (size_t)16 * K, BsW + 16 * 32);
    __syncthreads();
    short8 af[4], bfr[4];
    int csw = (quad ^ (l16 & 3)) * 8;                // swizzled read chunk
    for (int im = 0; im < 4; im++)
      af[im] = *(const short8*)(As + (wr * 64 + im * 16 + l16) * 32 + csw);
    for (int in = 0; in < 4; in++)
      bfr[in] = *(const short8*)(Bs + (wc * 64 + in * 16 + l16) * 32 + csw);
    for (int im = 0; im < 4; im++)
      for (int in = 0; in < 4; in++)
        acc[im][in] = __builtin_amdgcn_mfma_f32_16x16x32_bf16(af[im], bfr[in], acc[im][in], 0, 0, 0);
  }

  for (int im = 0; im < 4; im++){
    int row = m0 + wr * 64 + im * 16 + quad * 4;
    for (int in = 0; in < 4; in++){
      int col = n0 + wc * 64 + in * 16 + l16;
      float bb = bias[col];
      f32x4 v = acc[im][in];
      for (int r = 0; r < 4; r++){
        float out = v[r] + bb;
        if (OUT_BF16) ((unsigned short*)Cout)[(size_t)(row + r) * N + col] = ftob(out);
        else          ((float*)Cout)[(size_t)(row + r) * N + col] = out;
      }
    }
  }
}

// ---------------- rmsnorm (bf16-faithful) + 3D rope ----------------
__global__ __launch_bounds__(256) void k_rmsnorm_rope(const unsigned short* __restrict__ QKVr,
        const float* __restrict__ gq, const float* __restrict__ gk,
        const int* __restrict__ grid_sizes, const float* __restrict__ freqs,
        unsigned short* __restrict__ Qh, unsigned short* __restrict__ Kh){
  int row = blockIdx.x;
  int which = blockIdx.y;
  int b = row >> 11, s = row & 2047;
  const unsigned short* xrow = QKVr + (size_t)row * 9216 + which * 3072;
  const float* g = which ? gk : gq;
  unsigned short* out = which ? Kh : Qh;

  int tid = threadIdx.x, w = tid >> 6, lane = tid & 63;
  float ss = 0.f;
  for (int i = tid; i < 3072; i += 256){
    float v = btof(xrow[i]);
    ss += btof(ftob(v * v));        // ref squares in bf16
  }
  for (int off = 32; off; off >>= 1) ss += __shfl_down(ss, off);
  __shared__ float red[4];
  if (lane == 0) red[w] = ss;
  __syncthreads();
  float tot = red[0] + red[1] + red[2] + red[3];
  float m = rb(tot * (1.0f / 3072.0f));
  m = rb(m + rb(1e-6f));
  float rn = rb(rsqrtf(m));

  int f = grid_sizes[b * 3], hh = grid_sizes[b * 3 + 1], ww = grid_sizes[b * 3 + 2];
  int fhw = f * hh * ww;

  for (int p = tid; p < 1536; p += 256){
    int c = p & 63, hd = p >> 6;
    int e0 = hd * 128 + 2 * c;
    float x0 = rb(btof(xrow[e0]) * rn) * rb(g[e0]);
    float x1 = rb(btof(xrow[e0 + 1]) * rn) * rb(g[e0 + 1]);
    float cs = 1.f, sn = 0.f;
    if (s < fhw){
      int pos;
      if (c < 22) pos = s / (hh * ww);          // C1 = 22
      else if (c < 43) pos = (s / ww) % hh;     // C2 = 21
      else pos = s % ww;                        // C3 = 21
      cs = freqs[(pos * 64 + c) * 2];
      sn = freqs[(pos * 64 + c) * 2 + 1];
    }
    float o0 = x0 * cs - x1 * sn;
    float o1 = x0 * sn + x1 * cs;
    size_t ob = ((size_t)((b * 24 + hd) * 2048 + s)) * 128 + 2 * c;
    out[ob]     = ftob(o0);
    out[ob + 1] = ftob(o1);
  }
}

// V: token-major -> Vt[bh][d][t]
__global__ __launch_bounds__(256) void k_build_vt(const unsigned short* __restrict__ QKVr,
                                                  unsigned short* __restrict__ Vt){
  __shared__ unsigned short tile[64][130];
  int bh = blockIdx.x;
  int b = bh / 24, h = bh % 24;
  int t0 = blockIdx.y * 64;
  for (int i = 0; i < 32; i++){
    int idx = i * 256 + threadIdx.x;
    int r = idx >> 7, c = idx & 127;
    tile[r][c] = QKVr[(size_t)(b * 2048 + t0 + r) * 9216 + 6144 + h * 128 + c];
  }
  __syncthreads();
  for (int i = 0; i < 32; i++){
    int idx = i * 256 + threadIdx.x;
    int d = idx >> 6, t = idx & 63;
    Vt[((size_t)bh * 128 + d) * 2048 + t0 + t] = tile[t][d];
  }
}

// ---------------- flash attention ----------------
// grid: x = q-tile (16), y = head (24), z = batch (2); 4 waves, 32 q-rows/wave.
// LDS swizzle: Ks rows 256B/16 chunks, chunk' = chunk ^ (row&15);
//              Vs/Ps rows 128B/8 chunks, chunk' = chunk ^ (row&7).
__global__ __launch_bounds__(256) void k_attn(const unsigned short* __restrict__ Q,
              const unsigned short* __restrict__ Kt, const unsigned short* __restrict__ Vt,
              const int* __restrict__ seq_lens, unsigned short* __restrict__ Obuf){
  int qt = blockIdx.x, h = blockIdx.y, b = blockIdx.z;
  int bh = b * 24 + h;
  int tid = threadIdx.x, w = tid >> 6, lane = tid & 63;
  int quad = lane >> 4, l16 = lane & 15;
  int sl = seq_lens[b];
  int nkt = (sl + 63) >> 6;

  __shared__ __align__(16) unsigned short Ks[64 * 128];   // [t][d] swizzled
  __shared__ __align__(16) unsigned short Vs[128 * 64];   // [d][t] swizzled
  __shared__ __align__(16) unsigned short Ps[4][32 * 64]; // per-wave P, swizzled

  const unsigned short* Qb = Q + ((size_t)bh * 2048 + qt * 128 + w * 32) * 128;
  short8 qf[2][4];
  for (int rt = 0; rt < 2; rt++)
    for (int ks = 0; ks < 4; ks++)
      qf[rt][ks] = *(const short8*)(Qb + (rt * 16 + l16) * 128 + ks * 32 + quad * 8);

  f32x4 o[2][8] = {};
  float mrow[2][4], lrow[2][4];
  for (int rt = 0; rt < 2; rt++)
    for (int r = 0; r < 4; r++){ mrow[rt][r] = -1e30f; lrow[rt][r] = 0.f; }

  const float ksc = 0.08838834764831845f * 1.4426950408889634f;  // scale*log2e

  const unsigned short* Kg0 = Kt + (size_t)bh * 2048 * 128;
  const unsigned short* Vg0 = Vt + (size_t)bh * 128 * 2048;

  int vrow = lane >> 3;                      // Vs staging: row within 8-row group
  int vchunk = (lane & 7) ^ (vrow & 7);      // swizzled global chunk for Vs

  for (int kt = 0; kt < nkt; kt++){
    int t0 = kt * 64;
    __syncthreads();
    for (int i = 0; i < 4; i++){              // K tile: 64 rows x 256B, 4 rows/wave-op
      int rowi = w * 16 + i * 4;
      int kchunk = l16 ^ (i * 4 + quad);      // swizzled global chunk (row&15 = i*4+quad)
      async_cp16(Kg0 + (size_t)(t0 + rowi + quad) * 128 + kchunk * 8,
                 (unsigned short*)Ks + rowi * 128);
    }
    for (int i = 0; i < 4; i++){              // Vt tile: 128 rows x 128B, 8 rows/wave-op
      int rowi = w * 32 + i * 8;
      async_cp16(Vg0 + (size_t)(rowi + vrow) * 2048 + t0 + vchunk * 8,
                 (unsigned short*)Vs + rowi * 64);
    }
    __syncthreads();

    f32x4 sac[2][4] = {};
    for (int ks = 0; ks < 4; ks++){
      int kcs = ((ks * 4 + quad) ^ l16) * 8;  // swizzled Ks read chunk
      short8 kf[4];
      for (int ct = 0; ct < 4; ct++)
        kf[ct] = *(const short8*)(Ks + (ct * 16 + l16) * 128 + kcs);
      __builtin_amdgcn_s_setprio(1);          // T5: pure-MFMA cluster
      for (int rt = 0; rt < 2; rt++)
        for (int ct = 0; ct < 4; ct++)
          sac[rt][ct] = __builtin_amdgcn_mfma_f32_16x16x32_bf16(qf[rt][ks], kf[ct], sac[rt][ct], 0, 0, 0);
      __builtin_amdgcn_s_setprio(0);
    }

    if (t0 + 64 > sl){                         // partial tile mask
      for (int ct = 0; ct < 4; ct++)
        if (t0 + ct * 16 + l16 >= sl)
          for (int rt = 0; rt < 2; rt++)
            for (int r = 0; r < 4; r++) sac[rt][ct][r] = -1e30f;
    }

    for (int rt = 0; rt < 2; rt++){
      for (int r = 0; r < 4; r++){
        float mx = fmaxf(fmaxf(sac[rt][0][r], sac[rt][1][r]), fmaxf(sac[rt][2][r], sac[rt][3][r]));
        mx = fmaxf(mx, __shfl_xor(mx, 1));
        mx = fmaxf(mx, __shfl_xor(mx, 2));
        mx = fmaxf(mx, __shfl_xor(mx, 4));
        mx = fmaxf(mx, __shfl_xor(mx, 8));
        float mnew = fmaxf(mrow[rt][r], mx);
        float alpha = exp2f((mrow[rt][r] - mnew) * ksc);
        mrow[rt][r] = mnew;
        float psum = 0.f;
        int pr = rt * 16 + quad * 4 + r;       // P row this lane writes
        int prsw = (quad * 4 + r) & 7;         // row&7 for swizzle
        for (int ct = 0; ct < 4; ct++){
          float p = exp2f((sac[rt][ct][r] - mnew) * ksc);
          unsigned short pb = ftob(p);
          psum += btof(pb);                    // l consistent with bf16 P used in PV
          int j = ct * 16 + l16;               // column
          int cidx = ((j >> 3) ^ prsw) * 8 + (j & 7);
          Ps[w][pr * 64 + cidx] = pb;
        }
        psum += __shfl_xor(psum, 1);
        psum += __shfl_xor(psum, 2);
        psum += __shfl_xor(psum, 4);
        psum += __shfl_xor(psum, 8);
        lrow[rt][r] = lrow[rt][r] * alpha + psum;
        for (int dt = 0; dt < 8; dt++) o[rt][dt][r] *= alpha;
      }
    }

    // wave-local: DS ops retire in order; fence compiler reordering + drain writes
    asm volatile("s_waitcnt lgkmcnt(0)" ::: "memory");

    for (int ks = 0; ks < 2; ks++){
      int vcs = ((ks * 4 + quad) ^ (l16 & 7)) * 8;  // swizzled Vs/Ps read chunk
      short8 vf[8];
      for (int dt = 0; dt < 8; dt++)
        vf[dt] = *(const short8*)(Vs + (dt * 16 + l16) * 64 + vcs);
      short8 pf[2];
      for (int rt = 0; rt < 2; rt++)
        pf[rt] = *(const short8*)(&Ps[w][(rt * 16 + l16) * 64 + vcs]);
      __builtin_amdgcn_s_setprio(1);          // T5: pure-MFMA cluster
      for (int rt = 0; rt < 2; rt++)
        for (int dt = 0; dt < 8; dt++)
          o[rt][dt] = __builtin_amdgcn_mfma_f32_16x16x32_bf16(pf[rt], vf[dt], o[rt][dt], 0, 0, 0);
      __builtin_amdgcn_s_setprio(0);
    }
  }

  for (int rt = 0; rt < 2; rt++){
    for (int r = 0; r < 4; r++){
      float inv = 1.0f / lrow[rt][r];
      int s = qt * 128 + w * 32 + rt * 16 + quad * 4 + r;
      size_t base = (size_t)(b * 2048 + s) * 3072 + h * 128;
      for (int dt = 0; dt < 8; dt++)
        Obuf[base + dt * 16 + l16] = ftob(o[rt][dt][r] * inv);
    }
  }
}

// ---------------- launch ----------------

extern "C" void kernel_launch(void* const* d_in, const int* in_sizes, int n_in,
                              void* d_out, int out_size, void* d_ws, size_t ws_size,
                              hipStream_t stream){
  const float* x          = (const float*)d_in[0];
  const int*   seq_lens   = (const int*)d_in[1];
  const int*   grid_sizes = (const int*)d_in[2];
  const float* freqs      = (const float*)d_in[3];
  const float* wq = (const float*)d_in[4];
  const float* bq = (const float*)d_in[5];
  const float* wk = (const float*)d_in[6];
  const float* bk = (const float*)d_in[7];
  const float* wv = (const float*)d_in[8];
  const float* bv = (const float*)d_in[9];
  const float* wo = (const float*)d_in[10];
  const float* bo = (const float*)d_in[11];
  const float* gq = (const float*)d_in[12];
  const float* gk = (const float*)d_in[13];

  char* ws = (char*)d_ws;
  unsigned short* Xb    = (unsigned short*)(ws);               // 25,165,824 B (also Obuf)
  unsigned short* WTqkv = (unsigned short*)(ws + 25165824);    // 56,623,104 B
  unsigned short* woT   = (unsigned short*)(ws + 81788928);    // 18,874,368 B
  float*          bias9 = (float*)(ws + 100663296);            //     36,864 B
  unsigned short* QKVr  = (unsigned short*)(ws + 100700160);   // 75,497,472 B
  unsigned short* Qh    = (unsigned short*)(ws + 176197632);   // 25,165,824 B
  unsigned short* Kh    = (unsigned short*)(ws + 201363456);   // 25,165,824 B
  unsigned short* Vth   = (unsigned short*)(ws + 226529280);   // 25,165,824 B
  unsigned short* Obuf  = Xb;                                  // Xb dead after QKV GEMM

  k_convert_x<<<12288, 256, 0, stream>>>(x, Xb);
  k_bias<<<36, 256, 0, stream>>>(bq, bk, bv, bias9);
  k_wt<<<dim3(48, 192), 256, 0, stream>>>(wq, wk, wv, wo, WTqkv, woT);
  k_gemm<true><<<dim3(72, 32), 256, 0, stream>>>(Xb, WTqkv, bias9, QKVr, 9216, 3072);
  k_rmsnorm_rope<<<dim3(4096, 2), 256, 0, stream>>>(QKVr, gq, gk, grid_sizes, freqs, Qh, Kh);
  k_build_vt<<<dim3(48, 32), 256, 0, stream>>>(QKVr, Vth);
  k_attn<<<dim3(16, 24, 2), 256, 0, stream>>>(Qh, Kh, Vth, seq_lens, Obuf);
  k_gemm<false><<<dim3(24, 32), 256, 0, stream>>>(Obuf, woT, bo, (float*)d_out, 3072, 3072);
}

// Round 2
// 1007.497 us; speedup vs baseline: 1.0364x; 1.0364x over previous
//
#include <hip/hip_runtime.h>
#include <stdint.h>
#include <stddef.h>

// WanSelfAttention on gfx950.
// R5: XOR chunk-swizzle on all LDS tiles; swizzle applied by permuting lane's
//     GLOBAL source address at staging (global_load_lds writes linearly).
// R6: T5 s_setprio around pure-MFMA clusters in k_attn.
// R7: k_attn software pipeline (T3/T4-lite): raw s_barrier + counted vmcnt so
//     K(t+1)/V(t) staging flies under softmax/PV instead of draining at a
//     __syncthreads vmcnt(0). Same 48KB LDS -> 3 blocks/CU retained.
//     + T13 defer-max rescale skip. + vectorized rope/build_vt (G13).

typedef __attribute__((ext_vector_type(8))) short short8;
typedef __attribute__((ext_vector_type(4))) float f32x4;
typedef __attribute__((ext_vector_type(4))) unsigned short ushort4v;
typedef __attribute__((address_space(1))) uint32_t gu32;
typedef __attribute__((address_space(3))) uint32_t lu32;

__device__ __forceinline__ float btof(unsigned short u){
  union { float f; uint32_t i; } x; x.i = ((uint32_t)u) << 16; return x.f;
}
__device__ __forceinline__ unsigned short ftob(float f){
  uint32_t u = __builtin_bit_cast(uint32_t, f);
  u += 0x7fffu + ((u >> 16) & 1u);   // RTNE (finite inputs only)
  return (unsigned short)(u >> 16);
}
__device__ __forceinline__ float rb(float f){ return btof(ftob(f)); }

__device__ __forceinline__ void async_cp16(const void* g, void* l){
  __builtin_amdgcn_global_load_lds((gu32*)g, (lu32*)l, 16, 0, 0);
}

__device__ __forceinline__ void barrier_raw(){
  asm volatile("" ::: "memory");
  __builtin_amdgcn_s_barrier();
  asm volatile("" ::: "memory");
}

// ---------------- converters ----------------

__global__ __launch_bounds__(256) void k_convert_x(const float* __restrict__ x,
                                                   unsigned short* __restrict__ xb){
  int i = (blockIdx.x * 256 + threadIdx.x) * 4;
  float4 v = *(const float4*)(x + i);
  ushort4v o = { ftob(v.x), ftob(v.y), ftob(v.z), ftob(v.w) };
  *(ushort4v*)(xb + i) = o;
}

__global__ __launch_bounds__(256) void k_bias(const float* __restrict__ bq,
                                              const float* __restrict__ bk,
                                              const float* __restrict__ bv,
                                              float* __restrict__ bias9){
  int i = blockIdx.x * 256 + threadIdx.x;     // 0..9215
  const float* s = (i < 3072) ? bq : ((i < 6144) ? bk : bv);
  bias9[i] = s[i % 3072];
}

// Transpose f32 weights (K x N, row-major) into bf16 W^T (N x K) rows.
__global__ __launch_bounds__(256) void k_wt(const float* __restrict__ wq,
                                            const float* __restrict__ wk,
                                            const float* __restrict__ wv,
                                            const float* __restrict__ wo,
                                            unsigned short* __restrict__ WTqkv,
                                            unsigned short* __restrict__ woT){
  __shared__ float tile[64][65];
  int k0 = blockIdx.x * 64;
  int n0g = blockIdx.y * 64;
  const float* src; unsigned short* dst; int col0, drow0;
  if (n0g < 9216){
    int sel = n0g / 3072;
    src = (sel == 0) ? wq : ((sel == 1) ? wk : wv);
    col0 = n0g % 3072; dst = WTqkv; drow0 = n0g;
  } else { src = wo; col0 = n0g - 9216; dst = woT; drow0 = n0g - 9216; }
  for (int i = 0; i < 16; i++){
    int idx = i * 256 + threadIdx.x;
    int r = idx >> 6, c = idx & 63;
    tile[r][c] = src[(size_t)(k0 + r) * 3072 + col0 + c];
  }
  __syncthreads();
  for (int i = 0; i < 16; i++){
    int idx = i * 256 + threadIdx.x;
    int rr = idx >> 6, cc = idx & 63;
    dst[(size_t)(drow0 + rr) * 3072 + k0 + cc] = ftob(tile[cc][rr]);
  }
}

// ---------------- GEMM: C[m][n] = sum_k A[m][k]*BT[n][k] + bias[n] ----------------
template <bool OUT_BF16>
__global__ __launch_bounds__(256) void k_gemm(const unsigned short* __restrict__ A,
                                              const unsigned short* __restrict__ BT,
                                              const float* __restrict__ bias,
                                              void* __restrict__ Cout, int N, int K){
  __shared__ __align__(16) unsigned short As[128 * 32];
  __shared__ __align__(16) unsigned short Bs[128 * 32];
  int tid = threadIdx.x;
  int w = tid >> 6, lane = tid & 63;
  int quad = lane >> 4, l16 = lane & 15;
  int m0 = blockIdx.y * 128, n0 = blockIdx.x * 128;
  int wr = w >> 1, wc = w & 1;

  f32x4 acc[4][4] = {};

  int srow = lane >> 2;                              // LDS row this lane fills
  int scol = ((lane & 3) ^ (srow & 3)) * 8;          // swizzled global chunk
  const unsigned short* Abase = A + (size_t)(m0 + w * 32 + srow) * K + scol;
  const unsigned short* Bbase = BT + (size_t)(n0 + w * 32 + srow) * K + scol;
  unsigned short* AsW = As + (w * 32) * 32;  // uniform per wave; HW adds lane*16B
  unsigned short* BsW = Bs + (w * 32) * 32;

  for (int kt = 0; kt < K; kt += 32){
    __syncthreads();
    async_cp16(Abase + kt, AsW);
    async_cp16(Abase + kt + (size_t)16 * K, AsW + 16 * 32);
    async_cp16(Bbase + kt, BsW);
    async_cp16(Bbase + kt + (size_t)16 * K, BsW + 16 * 32);
    __syncthreads();
    short8 af[4], bfr[4];
    int csw = (quad ^ (l16 & 3)) * 8;                // swizzled read chunk
    for (int im = 0; im < 4; im++)
      af[im] = *(const short8*)(As + (wr * 64 + im * 16 + l16) * 32 + csw);
    for (int in = 0; in < 4; in++)
      bfr[in] = *(const short8*)(Bs + (wc * 64 + in * 16 + l16) * 32 + csw);
    for (int im = 0; im < 4; im++)
      for (int in = 0; in < 4; in++)
        acc[im][in] = __builtin_amdgcn_mfma_f32_16x16x32_bf16(af[im], bfr[in], acc[im][in], 0, 0, 0);
  }

  for (int im = 0; im < 4; im++){
    int row = m0 + wr * 64 + im * 16 + quad * 4;
    for (int in = 0; in < 4; in++){
      int col = n0 + wc * 64 + in * 16 + l16;
      float bb = bias[col];
      f32x4 v = acc[im][in];
      for (int r = 0; r < 4; r++){
        float out = v[r] + bb;
        if (OUT_BF16) ((unsigned short*)Cout)[(size_t)(row + r) * N + col] = ftob(out);
        else          ((float*)Cout)[(size_t)(row + r) * N + col] = out;
      }
    }
  }
}

// ---------------- rmsnorm (bf16-faithful) + 3D rope ----------------
__global__ __launch_bounds__(256) void k_rmsnorm_rope(const unsigned short* __restrict__ QKVr,
        const float* __restrict__ gq, const float* __restrict__ gk,
        const int* __restrict__ grid_sizes, const float* __restrict__ freqs,
        unsigned short* __restrict__ Qh, unsigned short* __restrict__ Kh){
  int row = blockIdx.x;
  int which = blockIdx.y;
  int b = row >> 11, s = row & 2047;
  const unsigned short* xrow = QKVr + (size_t)row * 9216 + which * 3072;
  const float* g = which ? gk : gq;
  unsigned short* out = which ? Kh : Qh;

  int tid = threadIdx.x, w = tid >> 6, lane = tid & 63;
  float ss = 0.f;
  for (int i = tid * 4; i < 3072; i += 1024){      // vectorized: 3x ushort4
    ushort4v v = *(const ushort4v*)(xrow + i);
    for (int j = 0; j < 4; j++){
      float f = btof(v[j]);
      ss += btof(ftob(f * f));      // ref squares in bf16
    }
  }
  for (int off = 32; off; off >>= 1) ss += __shfl_down(ss, off);
  __shared__ float red[4];
  if (lane == 0) red[w] = ss;
  __syncthreads();
  float tot = red[0] + red[1] + red[2] + red[3];
  float m = rb(tot * (1.0f / 3072.0f));
  m = rb(m + rb(1e-6f));
  float rn = rb(rsqrtf(m));

  int f = grid_sizes[b * 3], hh = grid_sizes[b * 3 + 1], ww = grid_sizes[b * 3 + 2];
  int fhw = f * hh * ww;

  for (int p = tid; p < 1536; p += 256){
    int c = p & 63, hd = p >> 6;
    int e0 = hd * 128 + 2 * c;
    uint32_t xp = *(const uint32_t*)(xrow + e0);   // 2 bf16 packed
    float2 gg = *(const float2*)(g + e0);
    float x0 = rb(btof((unsigned short)(xp & 0xffffu)) * rn) * rb(gg.x);
    float x1 = rb(btof((unsigned short)(xp >> 16)) * rn) * rb(gg.y);
    float cs = 1.f, sn = 0.f;
    if (s < fhw){
      int pos;
      if (c < 22) pos = s / (hh * ww);          // C1 = 22
      else if (c < 43) pos = (s / ww) % hh;     // C2 = 21
      else pos = s % ww;                        // C3 = 21
      float2 f2 = *(const float2*)(freqs + (pos * 64 + c) * 2);
      cs = f2.x; sn = f2.y;
    }
    float o0 = x0 * cs - x1 * sn;
    float o1 = x0 * sn + x1 * cs;
    size_t ob = ((size_t)((b * 24 + hd) * 2048 + s)) * 128 + 2 * c;
    uint32_t op = ((uint32_t)ftob(o1) << 16) | (uint32_t)ftob(o0);
    *(uint32_t*)(out + ob) = op;
  }
}

// V: token-major -> Vt[bh][d][t]   (vectorized x4 on the global side)
__global__ __launch_bounds__(256) void k_build_vt(const unsigned short* __restrict__ QKVr,
                                                  unsigned short* __restrict__ Vt){
  __shared__ unsigned short tile[64][132];   // stride 132 u16 = 264B (8B aligned rows)
  int bh = blockIdx.x;
  int b = bh / 24, h = bh % 24;
  int t0 = blockIdx.y * 64;
  for (int i = 0; i < 8; i++){
    int idx = i * 1024 + threadIdx.x * 4;    // step 4 elems
    int r = idx >> 7, c = idx & 127;
    *(ushort4v*)&tile[r][c] =
      *(const ushort4v*)&QKVr[(size_t)(b * 2048 + t0 + r) * 9216 + 6144 + h * 128 + c];
  }
  __syncthreads();
  for (int i = 0; i < 8; i++){
    int idx = i * 1024 + threadIdx.x * 4;
    int d = idx >> 6, t = idx & 63;          // t multiple of 4
    ushort4v o4 = { tile[t][d], tile[t + 1][d], tile[t + 2][d], tile[t + 3][d] };
    *(ushort4v*)&Vt[((size_t)bh * 128 + d) * 2048 + t0 + t] = o4;
  }
}

// ---------------- flash attention ----------------
// grid: x = q-tile (16), y = head (24), z = batch (2); 4 waves, 32 q-rows/wave.
// Pipeline per KV tile t (raw barriers, counted vmcnt — no full drains):
//   [inv: Ks(t) resident]  issue Vs(t) | QK(t) | lgkm0,B1 | issue Ks(t+1) |
//   softmax(t) | vmcnt(4),B2 | PV(t) | lgkm0,vmcnt0,B3
__global__ __launch_bounds__(256) void k_attn(const unsigned short* __restrict__ Q,
              const unsigned short* __restrict__ Kt, const unsigned short* __restrict__ Vt,
              const int* __restrict__ seq_lens, unsigned short* __restrict__ Obuf){
  int qt = blockIdx.x, h = blockIdx.y, b = blockIdx.z;
  int bh = b * 24 + h;
  int tid = threadIdx.x, w = tid >> 6, lane = tid & 63;
  int quad = lane >> 4, l16 = lane & 15;
  int sl = seq_lens[b];
  int nkt = (sl + 63) >> 6;

  __shared__ __align__(16) unsigned short Ks[64 * 128];   // [t][d] swizzled
  __shared__ __align__(16) unsigned short Vs[128 * 64];   // [d][t] swizzled
  __shared__ __align__(16) unsigned short Ps[4][32 * 64]; // per-wave P, swizzled

  const unsigned short* Qb = Q + ((size_t)bh * 2048 + qt * 128 + w * 32) * 128;
  short8 qf[2][4];
  for (int rt = 0; rt < 2; rt++)
    for (int ks = 0; ks < 4; ks++)
      qf[rt][ks] = *(const short8*)(Qb + (rt * 16 + l16) * 128 + ks * 32 + quad * 8);

  f32x4 o[2][8] = {};
  float mrow[2][4], lrow[2][4];
  for (int rt = 0; rt < 2; rt++)
    for (int r = 0; r < 4; r++){ mrow[rt][r] = -1e30f; lrow[rt][r] = 0.f; }

  const float ksc = 0.08838834764831845f * 1.4426950408889634f;  // scale*log2e

  const unsigned short* Kg0 = Kt + (size_t)bh * 2048 * 128;
  const unsigned short* Vg0 = Vt + (size_t)bh * 128 * 2048;

  int vrow = lane >> 3;                      // Vs staging: row within 8-row group
  int vchunk = (lane & 7) ^ (vrow & 7);      // swizzled global chunk for Vs

  auto stageK = [&](int t0){
    for (int i = 0; i < 4; i++){              // K tile: 64 rows x 256B
      int rowi = w * 16 + i * 4;
      int kchunk = l16 ^ (i * 4 + quad);
      async_cp16(Kg0 + (size_t)(t0 + rowi + quad) * 128 + kchunk * 8,
                 (unsigned short*)Ks + rowi * 128);
    }
  };
  auto stageV = [&](int t0){
    for (int i = 0; i < 4; i++){              // Vt tile: 128 rows x 128B
      int rowi = w * 32 + i * 8;
      async_cp16(Vg0 + (size_t)(rowi + vrow) * 2048 + t0 + vchunk * 8,
                 (unsigned short*)Vs + rowi * 64);
    }
  };

  // prologue: K(0) resident before loop
  stageK(0);
  asm volatile("s_waitcnt vmcnt(0)" ::: "memory");
  barrier_raw();

  for (int kt = 0; kt < nkt; kt++){
    int t0 = kt * 64;

    stageV(t0);                               // 4 vm ops in flight (Vs(t))

    f32x4 sac[2][4] = {};
    for (int ks = 0; ks < 4; ks++){
      int kcs = ((ks * 4 + quad) ^ l16) * 8;  // swizzled Ks read chunk
      short8 kf[4];
      for (int ct = 0; ct < 4; ct++)
        kf[ct] = *(const short8*)(Ks + (ct * 16 + l16) * 128 + kcs);
      __builtin_amdgcn_s_setprio(1);          // T5: pure-MFMA cluster
      for (int rt = 0; rt < 2; rt++)
        for (int ct = 0; ct < 4; ct++)
          sac[rt][ct] = __builtin_amdgcn_mfma_f32_16x16x32_bf16(qf[rt][ks], kf[ct], sac[rt][ct], 0, 0, 0);
      __builtin_amdgcn_s_setprio(0);
    }

    asm volatile("s_waitcnt lgkmcnt(0)" ::: "memory");  // Ks reads retired
    barrier_raw();                            // B1: all waves done reading Ks(t)

    bool haveK = (kt + 1 < nkt);
    if (haveK) stageK(t0 + 64);               // +4 vm ops (Ks(t+1)), fly under softmax/PV

    if (t0 + 64 > sl){                        // partial tile mask
      for (int ct = 0; ct < 4; ct++)
        if (t0 + ct * 16 + l16 >= sl)
          for (int rt = 0; rt < 2; rt++)
            for (int r = 0; r < 4; r++) sac[rt][ct][r] = -1e30f;
    }

    for (int rt = 0; rt < 2; rt++){
      for (int r = 0; r < 4; r++){
        float mx = fmaxf(fmaxf(sac[rt][0][r], sac[rt][1][r]), fmaxf(sac[rt][2][r], sac[rt][3][r]));
        mx = fmaxf(mx, __shfl_xor(mx, 1));
        mx = fmaxf(mx, __shfl_xor(mx, 2));
        mx = fmaxf(mx, __shfl_xor(mx, 4));
        mx = fmaxf(mx, __shfl_xor(mx, 8));
        float mold = mrow[rt][r];
        float mnew;
        if (__all((mx - mold) * ksc <= 11.5f)){   // T13: defer-max, skip rescale
          mnew = mold;
        } else {
          mnew = fmaxf(mold, mx);
          float alpha = exp2f((mold - mnew) * ksc);
          mrow[rt][r] = mnew;
          lrow[rt][r] *= alpha;
          for (int dt = 0; dt < 8; dt++) o[rt][dt][r] *= alpha;
        }
        float psum = 0.f;
        int pr = rt * 16 + quad * 4 + r;       // P row this lane writes
        int prsw = (quad * 4 + r) & 7;         // row&7 for swizzle
        for (int ct = 0; ct < 4; ct++){
          float p = exp2f((sac[rt][ct][r] - mnew) * ksc);
          unsigned short pb = ftob(p);
          psum += btof(pb);                    // l consistent with bf16 P used in PV
          int j = ct * 16 + l16;               // column
          int cidx = ((j >> 3) ^ prsw) * 8 + (j & 7);
          Ps[w][pr * 64 + cidx] = pb;
        }
        psum += __shfl_xor(psum, 1);
        psum += __shfl_xor(psum, 2);
        psum += __shfl_xor(psum, 4);
        psum += __shfl_xor(psum, 8);
        lrow[rt][r] += psum;
      }
    }

    // own Vs(t) loads done (Ks(t+1) stays in flight), then make all waves' visible
    if (haveK) asm volatile("s_waitcnt vmcnt(4)" ::: "memory");
    else       asm volatile("s_waitcnt vmcnt(0)" ::: "memory");
    barrier_raw();                            // B2: Vs(t) visible block-wide

    asm volatile("s_waitcnt lgkmcnt(0)" ::: "memory");  // Ps writes drained (own wave)

    for (int ks = 0; ks < 2; ks++){
      int vcs = ((ks * 4 + quad) ^ (l16 & 7)) * 8;  // swizzled Vs/Ps read chunk
      short8 vf[8];
      for (int dt = 0; dt < 8; dt++)
        vf[dt] = *(const short8*)(Vs + (dt * 16 + l16) * 64 + vcs);
      short8 pf[2];
      for (int rt = 0; rt < 2; rt++)
        pf[rt] = *(const short8*)(&Ps[w][(rt * 16 + l16) * 64 + vcs]);
      __builtin_amdgcn_s_setprio(1);          // T5: pure-MFMA cluster
      for (int rt = 0; rt < 2; rt++)
        for (int dt = 0; dt < 8; dt++)
          o[rt][dt] = __builtin_amdgcn_mfma_f32_16x16x32_bf16(pf[rt], vf[dt], o[rt][dt], 0, 0, 0);
      __builtin_amdgcn_s_setprio(0);
    }

    asm volatile("s_waitcnt lgkmcnt(0)" ::: "memory");  // PV reads retired
    asm volatile("s_waitcnt vmcnt(0)" ::: "memory");    // Ks(t+1) landed (overlapped)
    barrier_raw();                            // B3: Vs free; Ks(t+1) visible
  }

  for (int rt = 0; rt < 2; rt++){
    for (int r = 0; r < 4; r++){
      float inv = 1.0f / lrow[rt][r];
      int s = qt * 128 + w * 32 + rt * 16 + quad * 4 + r;
      size_t base = (size_t)(b * 2048 + s) * 3072 + h * 128;
      for (int dt = 0; dt < 8; dt++)
        Obuf[base + dt * 16 + l16] = ftob(o[rt][dt][r] * inv);
    }
  }
}

// ---------------- launch ----------------

extern "C" void kernel_launch(void* const* d_in, const int* in_sizes, int n_in,
                              void* d_out, int out_size, void* d_ws, size_t ws_size,
                              hipStream_t stream){
  const float* x          = (const float*)d_in[0];
  const int*   seq_lens   = (const int*)d_in[1];
  const int*   grid_sizes = (const int*)d_in[2];
  const float* freqs      = (const float*)d_in[3];
  const float* wq = (const float*)d_in[4];
  const float* bq = (const float*)d_in[5];
  const float* wk = (const float*)d_in[6];
  const float* bk = (const float*)d_in[7];
  const float* wv = (const float*)d_in[8];
  const float* bv = (const float*)d_in[9];
  const float* wo = (const float*)d_in[10];
  const float* bo = (const float*)d_in[11];
  const float* gq = (const float*)d_in[12];
  const float* gk = (const float*)d_in[13];

  char* ws = (char*)d_ws;
  unsigned short* Xb    = (unsigned short*)(ws);               // 25,165,824 B (also Obuf)
  unsigned short* WTqkv = (unsigned short*)(ws + 25165824);    // 56,623,104 B
  unsigned short* woT   = (unsigned short*)(ws + 81788928);    // 18,874,368 B
  float*          bias9 = (float*)(ws + 100663296);            //     36,864 B
  unsigned short* QKVr  = (unsigned short*)(ws + 100700160);   // 75,497,472 B
  unsigned short* Qh    = (unsigned short*)(ws + 176197632);   // 25,165,824 B
  unsigned short* Kh    = (unsigned short*)(ws + 201363456);   // 25,165,824 B
  unsigned short* Vth   = (unsigned short*)(ws + 226529280);   // 25,165,824 B
  unsigned short* Obuf  = Xb;                                  // Xb dead after QKV GEMM

  k_convert_x<<<12288, 256, 0, stream>>>(x, Xb);
  k_bias<<<36, 256, 0, stream>>>(bq, bk, bv, bias9);
  k_wt<<<dim3(48, 192), 256, 0, stream>>>(wq, wk, wv, wo, WTqkv, woT);
  k_gemm<true><<<dim3(72, 32), 256, 0, stream>>>(Xb, WTqkv, bias9, QKVr, 9216, 3072);
  k_rmsnorm_rope<<<dim3(4096, 2), 256, 0, stream>>>(QKVr, gq, gk, grid_sizes, freqs, Qh, Kh);
  k_build_vt<<<dim3(48, 32), 256, 0, stream>>>(QKVr, Vth);
  k_attn<<<dim3(16, 24, 2), 256, 0, stream>>>(Qh, Kh, Vth, seq_lens, Obuf);
  k_gemm<false><<<dim3(24, 32), 256, 0, stream>>>(Obuf, woT, bo, (float*)d_out, 3072, 3072);
}